// Round 11
// baseline (70.524 us; speedup 1.0000x reference)
//
#include <hip/hip_runtime.h>

#define N_NODES 2048
#define F_IN 64
#define C_OUT 8
#define H_HID 32
#define G_NUM 16
#define NBLK 512
#define SFSW 512            // fsum LDS window width (cols)
#define MAGIC 0x5A5A6B6B    // != 0xAAAAAAAA poison

#define ALOADF(p)   __hip_atomic_load((p),  __ATOMIC_RELAXED, __HIP_MEMORY_SCOPE_AGENT)
#define ASTOREF(p,v) __hip_atomic_store((p), (v), __ATOMIC_RELAXED, __HIP_MEMORY_SCOPE_AGENT)

// ---------------------------------------------------------------------------
// Single dispatch, 512 blocks x 256 threads, fence-free producer/consumer.
//  blocks 0..255 : produce fsum for nodes 8b..8b+7 (relaxed agent atomic
//                  stores = write-through), then flagA[b]=MAGIC (relaxed;
//                  __syncthreads' vmcnt-drain orders data before flag)
//  all blocks    : 4 rows (1/wave); wave-parallel relaxed spin on flagA range,
//                  stage fsum window to LDS via relaxed agent atomic loads
//                  (NO acquire fence -> no cache invalidation), accumulate,
//                  relaxed-store rowout, flagB[b]=MAGIC
//  blocks 496+g  : spin flagB range, deterministic fixed-order readout of
//                  graph g via relaxed atomic loads, write out[g,:]
// All 512 blocks co-resident (67KB LDS, 128 VGPR -> 2 blocks/CU) => spins
// cannot deadlock. Replay-safe: stale MAGIC -> consumers read stale values
// that are bit-identical (pure function of unchanged inputs).
// ---------------------------------------------------------------------------
__global__ __launch_bounds__(256, 2) void fused_all(
    const float* __restrict__ x, const float* __restrict__ W1,
    const float* __restrict__ b1, const float* __restrict__ W2,
    const float* __restrict__ b2,
    const float* __restrict__ dist, const float* __restrict__ norm,
    const int* __restrict__ batch,
    const float* __restrict__ rW1, const float* __restrict__ rb1,
    const float* __restrict__ rW2, const float* __restrict__ rb2,
    float* fsum, float* rowout,
    int* flagA, int* flagB,
    float* __restrict__ out)
{
    __shared__ float sA[H_HID * 256];   // 32 KB: W1T tmp -> W2 c0..3 -> sFs window
    __shared__ float sB[H_HID * 256];   // 32 KB: W2 c4..7 ; winner reduce scratch
    __shared__ float sRW1[H_HID], sRB1[H_HID], sRW2[C_OUT * H_HID], sRB2[C_OUT];
    __shared__ int   sStarts[G_NUM + 1];

    const int tid = threadIdx.x;
    const int b   = blockIdx.x;
    const int wv  = tid >> 6, lane = tid & 63;

    // ---------------- phase 0 (all blocks): bounds + rho weights ----------
    for (int i = tid; i < N_NODES; i += 256) {
        const int cur  = batch[i];
        const int prev = (i == 0) ? -1 : batch[i - 1];
        for (int g = prev + 1; g <= cur; ++g) sStarts[g] = i;
        if (i == N_NODES - 1)
            for (int g = cur + 1; g <= G_NUM; ++g) sStarts[g] = N_NODES;
    }
    if (tid < H_HID) { sRW1[tid] = rW1[tid]; sRB1[tid] = rb1[tid]; }
    if (tid >= 64 && tid < 64 + C_OUT) sRB2[tid - 64] = rb2[tid - 64];
    if (tid >= 128) { const int k = tid - 128;
        sRW2[k] = rW2[k]; sRW2[k + 128] = rW2[k + 128]; }

    // ---------------- producer phase (blocks 0..255) -----------------------
    if (b < 256) {
        float* tmp = sA;
        #pragma unroll
        for (int k = 0; k < 8; ++k) {
            const int e  = tid + k * 256;          // e = f*32 + h
            const int f_ = e >> 5, h_ = e & 31;
            tmp[h_ * 65 + f_]        = W1[e];
            tmp[2080 + h_ * 65 + f_] = b1[e];
        }
        __syncthreads();

        float w1r[H_HID], b1r[H_HID];
        #pragma unroll
        for (int h = 0; h < H_HID; ++h) {
            w1r[h] = tmp[h * 65 + lane];
            b1r[h] = tmp[2080 + h * 65 + lane];
        }
        __syncthreads();

        #pragma unroll
        for (int k = 0; k < 16; ++k) {
            const int q = tid + k * 256;           // float4 index 0..4095
            const float4 v = *(const float4*)&W2[4 * q];
            const int h0 = (q & 7) * 4;
            const int c  = (q >> 3) & 7;
            const int ff = q >> 6;
            float* dst = (c < 4) ? sA : sB;
            const int col = (ff * 4 + (c & 3)) ^ ((q & 7) << 2);
            dst[(h0 + 0) * 256 + col] = v.x;
            dst[(h0 + 1) * 256 + col] = v.y;
            dst[(h0 + 2) * 256 + col] = v.z;
            dst[(h0 + 3) * 256 + col] = v.w;
        }
        __syncthreads();

        const int n0 = b * 8 + wv * 2;
        const float xv0 = x[n0 * F_IN + lane];
        const float xv1 = x[n0 * F_IN + F_IN + lane];

        float4 a00 = {0,0,0,0}, a01 = {0,0,0,0};
        float4 a10 = {0,0,0,0}, a11 = {0,0,0,0};
        #pragma unroll
        for (int h = 0; h < H_HID; ++h) {
            const float rv0 = fmaxf(fmaf(xv0, w1r[h], b1r[h]), 0.f);
            const float rv1 = fmaxf(fmaf(xv1, w1r[h], b1r[h]), 0.f);
            const int colx = (4 * lane) ^ ((h >> 2) << 2);
            const float4 wa = *(const float4*)&sA[h * 256 + colx];
            const float4 wb = *(const float4*)&sB[h * 256 + colx];
            a00.x = fmaf(rv0, wa.x, a00.x); a00.y = fmaf(rv0, wa.y, a00.y);
            a00.z = fmaf(rv0, wa.z, a00.z); a00.w = fmaf(rv0, wa.w, a00.w);
            a01.x = fmaf(rv0, wb.x, a01.x); a01.y = fmaf(rv0, wb.y, a01.y);
            a01.z = fmaf(rv0, wb.z, a01.z); a01.w = fmaf(rv0, wb.w, a01.w);
            a10.x = fmaf(rv1, wa.x, a10.x); a10.y = fmaf(rv1, wa.y, a10.y);
            a10.z = fmaf(rv1, wa.z, a10.z); a10.w = fmaf(rv1, wa.w, a10.w);
            a11.x = fmaf(rv1, wb.x, a11.x); a11.y = fmaf(rv1, wb.y, a11.y);
            a11.z = fmaf(rv1, wb.z, a11.z); a11.w = fmaf(rv1, wb.w, a11.w);
        }
        const float4 b2lo = *(const float4*)&b2[lane * C_OUT];
        const float4 b2hi = *(const float4*)&b2[lane * C_OUT + 4];
        a00.x += b2lo.x; a00.y += b2lo.y; a00.z += b2lo.z; a00.w += b2lo.w;
        a01.x += b2hi.x; a01.y += b2hi.y; a01.z += b2hi.z; a01.w += b2hi.w;
        a10.x += b2lo.x; a10.y += b2lo.y; a10.z += b2lo.z; a10.w += b2lo.w;
        a11.x += b2hi.x; a11.y += b2hi.y; a11.z += b2hi.z; a11.w += b2hi.w;

        float v0[C_OUT] = {a00.x,a00.y,a00.z,a00.w,a01.x,a01.y,a01.z,a01.w};
        float v1[C_OUT] = {a10.x,a10.y,a10.z,a10.w,a11.x,a11.y,a11.z,a11.w};
        #pragma unroll
        for (int c = 0; c < C_OUT; ++c) {
            float s0 = v0[c], s1 = v1[c];
            for (int off = 32; off; off >>= 1) {
                s0 += __shfl_down(s0, off);
                s1 += __shfl_down(s1, off);
            }
            v0[c] = s0; v1[c] = s1;
        }
        if (lane == 0) {
            #pragma unroll
            for (int c = 0; c < C_OUT; ++c) {
                ASTOREF(&fsum[n0 * C_OUT + c],       v0[c]);
                ASTOREF(&fsum[(n0 + 1) * C_OUT + c], v1[c]);
            }
        }
        __syncthreads();   // vmcnt-drain: all waves' fsum stores complete
        if (tid == 0)
            __hip_atomic_store(&flagA[b], MAGIC, __ATOMIC_RELAXED,
                               __HIP_MEMORY_SCOPE_AGENT);
    }

    // ---------------- row phase (all blocks): row i = b*4 + wv -------------
    {
        const int gmin = batch[b * 4], gmax = batch[b * 4 + 3];
        const int jsAll = sStarts[gmin];
        const int jeAll = sStarts[gmax + 1];

        // wave-parallel spin: wave 0, lane p polls flagA[pLo+p+64k]
        if (wv == 0) {
            const int pLo = jsAll >> 3;
            const int pHi = (jeAll + 7) >> 3;      // exclusive
            const int cnt = pHi - pLo;
            bool ok;
            do {
                ok = true;
                for (int p = pLo + lane; p < pHi; p += 64)
                    if (__hip_atomic_load(&flagA[p], __ATOMIC_RELAXED,
                                          __HIP_MEMORY_SCOPE_AGENT) != MAGIC)
                        ok = false;
                if (!__all(ok)) { __builtin_amdgcn_s_sleep(2); ok = false; }
            } while (!ok);
            (void)cnt;
        }
        __syncthreads();                            // sA free after producer use

        const int i  = b * 4 + wv;
        const int g  = batch[i];
        const int js = sStarts[g];
        const int je = sStarts[g + 1];

        float acc[C_OUT] = {0.f,0.f,0.f,0.f,0.f,0.f,0.f,0.f};

        for (int w0 = jsAll; w0 < jeAll; w0 += SFSW) {
            const int wlen = min(SFSW, jeAll - w0);
            // stage fsum window into sA via relaxed agent atomic loads
            for (int t = tid; t < wlen * C_OUT; t += 256) {
                const int jj = t >> 3, c = t & 7;
                sA[c * SFSW + jj] = ALOADF(&fsum[(w0 + jj) * C_OUT + c]);
            }
            __syncthreads();

            const int jstart = max(js, w0);
            const int jend   = min(je, w0 + wlen);
            for (int j = jstart + lane; j < jend; j += 64) {
                const float d  = dist[i * N_NODES + j];
                const float s  = 1.0f / (1.0f + d);
                const float nv = norm[i * N_NODES + j];
                const float invn = (nv == 0.0f) ? 1.0f : (1.0f / nv);

                float rho[C_OUT];
                #pragma unroll
                for (int c = 0; c < C_OUT; ++c) rho[c] = sRB2[c];
                #pragma unroll
                for (int h = 0; h < H_HID; ++h) {
                    const float rh = fmaxf(fmaf(s, sRW1[h], sRB1[h]), 0.f);
                    #pragma unroll
                    for (int c = 0; c < C_OUT; ++c)
                        rho[c] = fmaf(rh, sRW2[c * H_HID + h], rho[c]);
                }
                const int jw = j - w0;
                #pragma unroll
                for (int c = 0; c < C_OUT; ++c)
                    acc[c] = fmaf(rho[c] * invn, sA[c * SFSW + jw], acc[c]);
            }
            __syncthreads();                        // before window overwrite
        }

        #pragma unroll
        for (int c = 0; c < C_OUT; ++c) {
            float v = acc[c];
            for (int off = 32; off; off >>= 1) v += __shfl_down(v, off);
            acc[c] = v;
        }
        if (lane == 0) {
            #pragma unroll
            for (int c = 0; c < C_OUT; ++c)
                ASTOREF(&rowout[i * C_OUT + c], acc[c]);
        }
        __syncthreads();                            // vmcnt-drain rowout stores
        if (tid == 0)
            __hip_atomic_store(&flagB[b], MAGIC, __ATOMIC_RELAXED,
                               __HIP_MEMORY_SCOPE_AGENT);
    }

    // ---------------- readout phase (blocks 496..511) ----------------------
    if (b >= NBLK - G_NUM) {
        const int g2 = b - (NBLK - G_NUM);
        const int is = sStarts[g2];
        const int ie = sStarts[g2 + 1];

        if (ie <= is) {
            if (tid < C_OUT) out[g2 * C_OUT + tid] = 0.0f;
            return;
        }

        if (wv == 0) {
            const int pLo = is >> 2;
            const int pHi = (ie + 3) >> 2;
            bool ok;
            do {
                ok = true;
                for (int p = pLo + lane; p < pHi; p += 64)
                    if (__hip_atomic_load(&flagB[p], __ATOMIC_RELAXED,
                                          __HIP_MEMORY_SCOPE_AGENT) != MAGIC)
                        ok = false;
                if (!__all(ok)) { __builtin_amdgcn_s_sleep(2); ok = false; }
            } while (!ok);
        }
        __syncthreads();

        // deterministic segment sum: part = tid>>3 (32 parts), c = tid&7
        float s = 0.f;
        for (int r = is + (tid >> 3); r < ie; r += 32)
            s += ALOADF(&rowout[r * C_OUT + (tid & 7)]);
        sB[tid] = s;
        __syncthreads();
        if (tid < C_OUT) {
            float t = 0.f;
            for (int p = 0; p < 32; ++p) t += sB[p * C_OUT + tid];
            out[g2 * C_OUT + tid] = t;
        }
    }
}

extern "C" void kernel_launch(void* const* d_in, const int* in_sizes, int n_in,
                              void* d_out, int out_size, void* d_ws, size_t ws_size,
                              hipStream_t stream)
{
    const float* x    = (const float*)d_in[0];
    const float* dist = (const float*)d_in[1];
    const float* norm = (const float*)d_in[2];
    const int*   batch= (const int*)d_in[3];
    const float* fsW1 = (const float*)d_in[4];
    const float* fsb1 = (const float*)d_in[5];
    const float* fsW2 = (const float*)d_in[6];
    const float* fsb2 = (const float*)d_in[7];
    const float* rW1  = (const float*)d_in[8];
    const float* rb1  = (const float*)d_in[9];
    const float* rW2  = (const float*)d_in[10];
    const float* rb2  = (const float*)d_in[11];
    float* out = (float*)d_out;

    float* fsum   = (float*)d_ws;                       // N*C floats
    float* rowout = fsum + N_NODES * C_OUT;             // N*C floats
    int*   flagA  = (int*)(rowout + N_NODES * C_OUT);   // 256 ints
    int*   flagB  = flagA + 256;                        // 512 ints

    fused_all<<<NBLK, 256, 0, stream>>>(x, fsW1, fsb1, fsW2, fsb2,
                                        dist, norm, batch,
                                        rW1, rb1, rW2, rb2,
                                        fsum, rowout, flagA, flagB, out);
}

// Round 12
// 43.765 us; speedup vs baseline: 1.6114x; 1.6114x over previous
//
#include <hip/hip_runtime.h>

#define N_NODES 2048
#define F_IN 64
#define C_OUT 8
#define H_HID 32
#define G_NUM 16
#define CHUNK 32
#define NCB   64      // column chunks
#define NRB   8       // row slices per chunk
#define NBLK2 (NCB * NRB)   // K2 grid = 512
#define AL(p)    __hip_atomic_load((p),  __ATOMIC_RELAXED, __HIP_MEMORY_SCOPE_AGENT)
#define AS(p,v)  __hip_atomic_store((p), (v), __ATOMIC_RELAXED, __HIP_MEMORY_SCOPE_AGENT)

// ---------------------------------------------------------------------------
// K1 (R8-proven): blocks [0,256): fsum for 8 nodes each. Block 256: graph
// bounds into ws + zero the K2 arrival counter.
// ---------------------------------------------------------------------------
__global__ __launch_bounds__(256) void fsum_bounds_kernel(
    const float* __restrict__ x, const float* __restrict__ W1,
    const float* __restrict__ b1, const float* __restrict__ W2,
    const float* __restrict__ b2, float* __restrict__ fsum,
    const int* __restrict__ batch, int* __restrict__ starts,
    int* __restrict__ counter)
{
    const int tid = threadIdx.x;

    if (blockIdx.x >= 256) {
        for (int i = tid; i < N_NODES; i += 256) {
            const int cur  = batch[i];
            const int prev = (i == 0) ? -1 : batch[i - 1];
            for (int g = prev + 1; g <= cur; ++g) starts[g] = i;
            if (i == N_NODES - 1)
                for (int g = cur + 1; g <= G_NUM; ++g) starts[g] = N_NODES;
        }
        if (tid == 0) counter[0] = 0;       // fresh arrival counter every call
        return;
    }

    __shared__ float sA[H_HID * 256];   // 32 KB : W2 c0..3 swizzled (tmp W1T)
    __shared__ float sB[H_HID * 256];   // 32 KB : W2 c4..7 swizzled
    float* tmp = sA;

    #pragma unroll
    for (int k = 0; k < 8; ++k) {
        const int e  = tid + k * 256;          // e = f*32 + h
        const int f_ = e >> 5, h_ = e & 31;
        tmp[h_ * 65 + f_]        = W1[e];
        tmp[2080 + h_ * 65 + f_] = b1[e];
    }
    __syncthreads();

    const int wv = tid >> 6;                   // wave -> node pair
    const int f  = tid & 63;                   // lane -> feature
    float w1r[H_HID], b1r[H_HID];
    #pragma unroll
    for (int h = 0; h < H_HID; ++h) {
        w1r[h] = tmp[h * 65 + f];
        b1r[h] = tmp[2080 + h * 65 + f];
    }
    __syncthreads();

    #pragma unroll
    for (int k = 0; k < 16; ++k) {
        const int q = tid + k * 256;           // float4 index, 0..4095
        const float4 v = *(const float4*)&W2[4 * q];
        const int h0 = (q & 7) * 4;
        const int c  = (q >> 3) & 7;
        const int ff = q >> 6;
        float* dst = (c < 4) ? sA : sB;
        const int col = (ff * 4 + (c & 3)) ^ ((q & 7) << 2);
        dst[(h0 + 0) * 256 + col] = v.x;
        dst[(h0 + 1) * 256 + col] = v.y;
        dst[(h0 + 2) * 256 + col] = v.z;
        dst[(h0 + 3) * 256 + col] = v.w;
    }
    __syncthreads();

    const int n0 = blockIdx.x * 8 + wv * 2;
    const float xv0 = x[n0 * F_IN + f];
    const float xv1 = x[n0 * F_IN + F_IN + f];

    float4 a00 = {0,0,0,0}, a01 = {0,0,0,0};
    float4 a10 = {0,0,0,0}, a11 = {0,0,0,0};
    #pragma unroll
    for (int h = 0; h < H_HID; ++h) {
        const float rv0 = fmaxf(fmaf(xv0, w1r[h], b1r[h]), 0.f);
        const float rv1 = fmaxf(fmaf(xv1, w1r[h], b1r[h]), 0.f);
        const int colx = (4 * f) ^ ((h >> 2) << 2);
        const float4 wa = *(const float4*)&sA[h * 256 + colx];
        const float4 wb = *(const float4*)&sB[h * 256 + colx];
        a00.x = fmaf(rv0, wa.x, a00.x); a00.y = fmaf(rv0, wa.y, a00.y);
        a00.z = fmaf(rv0, wa.z, a00.z); a00.w = fmaf(rv0, wa.w, a00.w);
        a01.x = fmaf(rv0, wb.x, a01.x); a01.y = fmaf(rv0, wb.y, a01.y);
        a01.z = fmaf(rv0, wb.z, a01.z); a01.w = fmaf(rv0, wb.w, a01.w);
        a10.x = fmaf(rv1, wa.x, a10.x); a10.y = fmaf(rv1, wa.y, a10.y);
        a10.z = fmaf(rv1, wa.z, a10.z); a10.w = fmaf(rv1, wa.w, a10.w);
        a11.x = fmaf(rv1, wb.x, a11.x); a11.y = fmaf(rv1, wb.y, a11.y);
        a11.z = fmaf(rv1, wb.z, a11.z); a11.w = fmaf(rv1, wb.w, a11.w);
    }
    const float4 b2lo = *(const float4*)&b2[f * C_OUT];
    const float4 b2hi = *(const float4*)&b2[f * C_OUT + 4];
    a00.x += b2lo.x; a00.y += b2lo.y; a00.z += b2lo.z; a00.w += b2lo.w;
    a01.x += b2hi.x; a01.y += b2hi.y; a01.z += b2hi.z; a01.w += b2hi.w;
    a10.x += b2lo.x; a10.y += b2lo.y; a10.z += b2lo.z; a10.w += b2lo.w;
    a11.x += b2hi.x; a11.y += b2hi.y; a11.z += b2hi.z; a11.w += b2hi.w;

    float v0[C_OUT] = {a00.x,a00.y,a00.z,a00.w,a01.x,a01.y,a01.z,a01.w};
    float v1[C_OUT] = {a10.x,a10.y,a10.z,a10.w,a11.x,a11.y,a11.z,a11.w};
    #pragma unroll
    for (int c = 0; c < C_OUT; ++c) {
        float s0 = v0[c], s1 = v1[c];
        for (int off = 32; off; off >>= 1) {
            s0 += __shfl_down(s0, off);
            s1 += __shfl_down(s1, off);
        }
        v0[c] = s0; v1[c] = s1;
    }
    if (f == 0) {
        *(float4*)&fsum[n0 * C_OUT]           = make_float4(v0[0],v0[1],v0[2],v0[3]);
        *(float4*)&fsum[n0 * C_OUT + 4]       = make_float4(v0[4],v0[5],v0[6],v0[7]);
        *(float4*)&fsum[(n0 + 1) * C_OUT]     = make_float4(v1[0],v1[1],v1[2],v1[3]);
        *(float4*)&fsum[(n0 + 1) * C_OUT + 4] = make_float4(v1[4],v1[5],v1[6],v1[7]);
    }
}

// ---------------------------------------------------------------------------
// K2 (colsum form): 512 blocks = 64 column-chunks x 8 row-slices.
// Block (cb, rb): for each graph g overlapping chunk cols [32cb,32cb+32):
//   part[g][b][c] = sum_{j in chunk∩g} fsum[j,c] *
//                   sum_{i in g, i-slice rb} rho(i,j,c)/norm_safe(i,j)
// Slots stored agent-relaxed (bypass non-coherent L2; ~64 B/block).
// Last-arriving block (relaxed agent fetch_add == 511) reads slots in fixed
// (cb, rb) order and writes out -> bit-deterministic, no spins, no fences.
// ---------------------------------------------------------------------------
__global__ __launch_bounds__(256) void colsum_readout_kernel(
    const float* __restrict__ dist, const float* __restrict__ norm,
    const int* __restrict__ batch, const int* __restrict__ starts,
    const float* __restrict__ rW1, const float* __restrict__ rb1,
    const float* __restrict__ rW2, const float* __restrict__ rb2,
    const float* __restrict__ fsum, float* part, int* counter,
    float* __restrict__ out)
{
    __shared__ float sW1[H_HID], sb1[H_HID], sW2[C_OUT * H_HID], sb2[C_OUT];
    __shared__ float sFs[C_OUT * CHUNK];
    __shared__ float sRed[4][C_OUT];
    __shared__ int   sStarts[G_NUM + 1];
    __shared__ int   sWin;
    __shared__ float sAcc[256];

    const int tid = threadIdx.x;
    const int b   = blockIdx.x;
    const int cb  = b >> 3, rb = b & 7;
    const int j0  = cb * CHUNK;
    const int wv  = tid >> 6, lane = tid & 63;

    // ---- staging ----
    if (tid < H_HID) { sW1[tid] = rW1[tid]; sb1[tid] = rb1[tid]; }
    if (tid >= 64 && tid < 64 + C_OUT) sb2[tid - 64] = rb2[tid - 64];
    if (tid >= 96 && tid < 96 + G_NUM + 1) sStarts[tid - 96] = starts[tid - 96];
    if (tid >= 128) { const int k = tid - 128;
        sW2[k] = rW2[k]; sW2[k + 128] = rW2[k + 128]; }
    {   // fsum slice for own columns: 1 KB, coalesced
        const int jj = tid >> 3, c = tid & 7;
        sFs[c * CHUNK + jj] = fsum[(j0 + jj) * C_OUT + c];
    }
    __syncthreads();

    const int gs = batch[j0], ge = batch[j0 + CHUNK - 1];
    const int jj = lane & 31, hf = lane >> 5;
    const int j  = j0 + jj;

    for (int g = gs; g <= ge; ++g) {
        const int is = sStarts[g], ie = sStarts[g + 1];
        const int jlo = max(j0, is), jhi = min(j0 + CHUNK, ie);
        const bool actj = (j >= jlo) && (j < jhi);
        const int glen = ie - is;

        float acc[C_OUT] = {0,0,0,0,0,0,0,0};
        for (int r = rb * 8 + wv * 2 + hf; r < glen; r += 64) {
            if (actj) {
                const int i = is + r;
                const float d  = dist[i * N_NODES + j];
                const float s  = 1.0f / (1.0f + d);
                const float nv = norm[i * N_NODES + j];
                const float invn = (nv == 0.0f) ? 1.0f : (1.0f / nv);

                float rho[C_OUT];
                #pragma unroll
                for (int c = 0; c < C_OUT; ++c) rho[c] = sb2[c];
                #pragma unroll
                for (int h = 0; h < H_HID; ++h) {
                    const float rh = fmaxf(fmaf(s, sW1[h], sb1[h]), 0.f);
                    #pragma unroll
                    for (int c = 0; c < C_OUT; ++c)
                        rho[c] = fmaf(rh, sW2[c * H_HID + h], rho[c]);
                }
                #pragma unroll
                for (int c = 0; c < C_OUT; ++c)
                    acc[c] = fmaf(rho[c] * invn, sFs[c * CHUNK + jj], acc[c]);
            }
        }

        #pragma unroll
        for (int c = 0; c < C_OUT; ++c) {
            float v = acc[c];
            for (int off = 32; off; off >>= 1) v += __shfl_down(v, off);
            acc[c] = v;
        }
        if (lane == 0) {
            #pragma unroll
            for (int c = 0; c < C_OUT; ++c) sRed[wv][c] = acc[c];
        }
        __syncthreads();
        if (tid < C_OUT) {
            const float s4 = sRed[0][tid] + sRed[1][tid]
                           + sRed[2][tid] + sRed[3][tid];
            AS(&part[(g * NBLK2 + b) * C_OUT + tid], s4);
        }
        __syncthreads();
    }

    // ---- arrival; last block performs deterministic readout ----
    __syncthreads();                 // drains all threads' slot stores (vmcnt 0)
    if (tid == 0) {
        const int old = __hip_atomic_fetch_add(counter, 1, __ATOMIC_RELAXED,
                                               __HIP_MEMORY_SCOPE_AGENT);
        sWin = (old == NBLK2 - 1) ? 1 : 0;
    }
    __syncthreads();
    if (!sWin) return;

    for (int g = 0; g < G_NUM; ++g) {
        const int is = sStarts[g], ie = sStarts[g + 1];
        if (is >= ie) {
            if (tid < C_OUT) out[g * C_OUT + tid] = 0.0f;
            __syncthreads();
            continue;
        }
        const int bLo = (is >> 5) * NRB;
        const int bHi = (((ie - 1) >> 5) + 1) * NRB;    // exclusive
        float t = 0.0f;
        for (int b2 = bLo + (tid >> 3); b2 < bHi; b2 += 32)
            t += AL(&part[(g * NBLK2 + b2) * C_OUT + (tid & 7)]);
        sAcc[tid] = t;
        __syncthreads();
        if (tid < C_OUT) {
            float s = 0.0f;
            for (int p = 0; p < 32; ++p) s += sAcc[p * C_OUT + tid];
            out[g * C_OUT + tid] = s;
        }
        __syncthreads();
    }
}

extern "C" void kernel_launch(void* const* d_in, const int* in_sizes, int n_in,
                              void* d_out, int out_size, void* d_ws, size_t ws_size,
                              hipStream_t stream)
{
    const float* x    = (const float*)d_in[0];
    const float* dist = (const float*)d_in[1];
    const float* norm = (const float*)d_in[2];
    const int*   batch= (const int*)d_in[3];
    const float* fsW1 = (const float*)d_in[4];
    const float* fsb1 = (const float*)d_in[5];
    const float* fsW2 = (const float*)d_in[6];
    const float* fsb2 = (const float*)d_in[7];
    const float* rW1  = (const float*)d_in[8];
    const float* rb1  = (const float*)d_in[9];
    const float* rW2  = (const float*)d_in[10];
    const float* rb2  = (const float*)d_in[11];
    float* out = (float*)d_out;

    float* fsum    = (float*)d_ws;                        // 2048*8 floats
    int*   starts  = (int*)(fsum + N_NODES * C_OUT);      // 17 ints (pad 32)
    int*   counter = starts + 32;                         // 1 int (pad 32)
    float* part    = (float*)(counter + 32);              // 16*512*8 floats

    fsum_bounds_kernel<<<257, 256, 0, stream>>>(x, fsW1, fsb1, fsW2, fsb2,
                                                fsum, batch, starts, counter);
    colsum_readout_kernel<<<NBLK2, 256, 0, stream>>>(dist, norm, batch, starts,
                                                     rW1, rb1, rW2, rb2,
                                                     fsum, part, counter, out);
}